// Round 6
// baseline (173.032 us; speedup 1.0000x reference)
//
#include <hip/hip_runtime.h>
#include <hip/hip_bf16.h>
#include <math.h>

#define DIN 512
#define DIM 512
#define NHEADS 8
#define DHEAD 64
#define NB 32
#define NPAD 512              // per-graph padded node slots
#define NPTOT (NB * NPAD)     // 16384

typedef __attribute__((ext_vector_type(8))) short bf16x8;
typedef __attribute__((ext_vector_type(8))) unsigned short u16x8;
typedef __attribute__((ext_vector_type(4))) float f32x4;

typedef __attribute__((address_space(3))) unsigned int lds_u32;
typedef __attribute__((address_space(1))) const unsigned int g_u32;

__device__ __forceinline__ void gll16(const unsigned short* g, unsigned short* l) {
  __builtin_amdgcn_global_load_lds((g_u32*)g, (lds_u32*)l, 16, 0, 0);
}

__device__ inline unsigned short f2bf(float x) {
  unsigned int u = __float_as_uint(x);
  unsigned int r = (u + 0x7FFFu + ((u >> 16) & 1u)) >> 16;
  return (unsigned short)r;
}

// ---------------- fused prep: LN rows | starts+map | 4 weight transposes ----------------
__global__ __launch_bounds__(256) void prep_kernel(const float* __restrict__ z,
                                                   const float* __restrict__ gamma,
                                                   const float* __restrict__ beta,
                                                   const int* __restrict__ src,
                                                   const float* __restrict__ Wq,
                                                   const float* __restrict__ Wk,
                                                   const float* __restrict__ Wv,
                                                   const float* __restrict__ Wo,
                                                   unsigned short* __restrict__ zn,
                                                   int* __restrict__ starts,
                                                   int* __restrict__ dstrow,
                                                   unsigned short* __restrict__ WtQKV,
                                                   unsigned short* __restrict__ WtO,
                                                   int ntot) {
  __shared__ float tile[32][33];
  int b = blockIdx.x;
  int nln = ntot >> 2;
  int nmap = (ntot + 255) >> 8;
  if (b < nln) {
    // ---- LayerNorm: one wave per row ----
    int wave = b * 4 + (threadIdx.x >> 6);
    int lane = threadIdx.x & 63;
    const float* row = z + (size_t)wave * DIN;
    float4 a = ((const float4*)row)[lane];
    float4 bb = ((const float4*)row)[64 + lane];
    float s  = a.x + a.y + a.z + a.w + bb.x + bb.y + bb.z + bb.w;
    float sq = a.x*a.x + a.y*a.y + a.z*a.z + a.w*a.w
             + bb.x*bb.x + bb.y*bb.y + bb.z*bb.z + bb.w*bb.w;
#pragma unroll
    for (int off = 32; off; off >>= 1) {
      s  += __shfl_xor(s, off);
      sq += __shfl_xor(sq, off);
    }
    float mu  = s * (1.0f / DIN);
    float var = sq * (1.0f / DIN) - mu * mu;
    float r   = rsqrtf(var + 1e-5f);
    float4 g0 = ((const float4*)gamma)[lane];
    float4 g1 = ((const float4*)gamma)[64 + lane];
    float4 b0 = ((const float4*)beta)[lane];
    float4 b1 = ((const float4*)beta)[64 + lane];
    ushort4 o0, o1;
    o0.x = f2bf((a.x - mu) * r * g0.x + b0.x);
    o0.y = f2bf((a.y - mu) * r * g0.y + b0.y);
    o0.z = f2bf((a.z - mu) * r * g0.z + b0.z);
    o0.w = f2bf((a.w - mu) * r * g0.w + b0.w);
    o1.x = f2bf((bb.x - mu) * r * g1.x + b1.x);
    o1.y = f2bf((bb.y - mu) * r * g1.y + b1.y);
    o1.z = f2bf((bb.z - mu) * r * g1.z + b1.z);
    o1.w = f2bf((bb.w - mu) * r * g1.w + b1.w);
    ((ushort4*)(zn + (size_t)wave * DIN))[lane] = o0;
    ((ushort4*)(zn + (size_t)wave * DIN))[64 + lane] = o1;
  } else if (b < nln + nmap) {
    int bid = b - nln;
    if (bid == 0 && threadIdx.x <= NB) {
      int gg = threadIdx.x;
      int lo = 0, hi = ntot;
      while (lo < hi) { int mid = (lo + hi) >> 1; if (src[mid] < gg) lo = mid + 1; else hi = mid; }
      starts[gg] = lo;
    }
    int i = bid * 256 + threadIdx.x;
    if (i < ntot) {
      int gg = src[i];
      int lo = 0, hi = ntot;
      while (lo < hi) { int mid = (lo + hi) >> 1; if (src[mid] < gg) lo = mid + 1; else hi = mid; }
      dstrow[i] = gg * NPAD + (i - lo);
    }
  } else {
    int idx = b - nln - nmap;              // 0..1023
    int zz = idx >> 8;
    int rem = idx & 255;
    const float* W; unsigned short* Wt;
    if (zz == 0)      { W = Wq; Wt = WtQKV; }
    else if (zz == 1) { W = Wk; Wt = WtQKV + (size_t)512 * DIN; }
    else if (zz == 2) { W = Wv; Wt = WtQKV + (size_t)1024 * DIN; }
    else              { W = Wo; Wt = WtO; }
    int k0 = (rem & 15) * 32;
    int n0 = (rem >> 4) * 32;
    int tx = threadIdx.x & 31;
    int ty = threadIdx.x >> 5;
#pragma unroll
    for (int i = 0; i < 4; i++)
      tile[ty + i * 8][tx] = W[(size_t)(k0 + ty + i * 8) * DIM + n0 + tx];
    __syncthreads();
#pragma unroll
    for (int i = 0; i < 4; i++)
      Wt[(size_t)(n0 + ty + i * 8) * DIN + k0 + tx] = f2bf(tile[tx][ty + i * 8]);
  }
}

// ---------------- m97-style staged GEMM: C[m][n] = sum_k A[m][k] * Bt[n][k], K=512 ----------------
// 128x128x32 tiles, dbuf global_load_lds; both epilogues LDS-transposed -> coalesced wide stores.
template <int NCOLS, bool BIAS, bool OUT_F32, bool REMAP>
__global__ __launch_bounds__(256) void gemm_staged(const unsigned short* __restrict__ A,
                                                   const unsigned short* __restrict__ Bt,
                                                   const float* __restrict__ bias,
                                                   const int* __restrict__ remap,
                                                   unsigned short* __restrict__ Cbf,
                                                   float* __restrict__ Cf) {
  __shared__ unsigned short smem[16384];   // loop: A dbuf [0,8192) + B dbuf [8192,16384); epilogue: C tile
  int tid = threadIdx.x, lane = tid & 63, wv = tid >> 6;
  int col = lane & 15, quad = lane >> 4;
  int m0 = blockIdx.x * 128, n0 = blockIdx.y * 128;
  int msub = (wv & 1) * 64, nsub = (wv >> 1) * 64;

  int srow = lane >> 2;                                   // 0..15
  int cswz = (((lane & 3) ^ ((lane >> 3) & 3))) * 8;      // swizzled k-chunk (ushorts)

  f32x4 acc[4][4];
#pragma unroll
  for (int i = 0; i < 4; i++)
#pragma unroll
    for (int j = 0; j < 4; j++) acc[i][j] = (f32x4){0.f, 0.f, 0.f, 0.f};

  auto stage = [&](int ks, int nb) {
    const unsigned short* Ab = A  + (size_t)m0 * DIN + ks * 32;
    const unsigned short* Bb = Bt + (size_t)n0 * DIN + ks * 32;
#pragma unroll
    for (int i = 0; i < 2; i++) {
      int t = wv * 2 + i;  // 0..7 -> rows t*16..t*16+16
      gll16(Ab + (size_t)(t * 16 + srow) * DIN + cswz, smem + nb * 4096 + t * 512);
      gll16(Bb + (size_t)(t * 16 + srow) * DIN + cswz, smem + 8192 + nb * 4096 + t * 512);
    }
  };

  stage(0, 0);
#pragma unroll 2
  for (int ks = 0; ks < 16; ks++) {
    int cur = ks & 1;
    __syncthreads();
    if (ks + 1 < 16) stage(ks + 1, 1 - cur);
    bf16x8 af[4], bfr[4];
#pragma unroll
    for (int mt = 0; mt < 4; mt++) {
      int row = msub + mt * 16 + col;
      af[mt] = *(const bf16x8*)&smem[cur * 4096 + row * 32 + ((quad ^ ((row >> 1) & 3)) * 8)];
    }
#pragma unroll
    for (int nt = 0; nt < 4; nt++) {
      int row = nsub + nt * 16 + col;
      bfr[nt] = *(const bf16x8*)&smem[8192 + cur * 4096 + row * 32 + ((quad ^ ((row >> 1) & 3)) * 8)];
    }
#pragma unroll
    for (int mt = 0; mt < 4; mt++)
#pragma unroll
      for (int nt = 0; nt < 4; nt++)
        acc[mt][nt] = __builtin_amdgcn_mfma_f32_16x16x32_bf16(af[mt], bfr[nt], acc[mt][nt], 0, 0, 0);
  }

  if (!OUT_F32) {
    // ---- bf16 epilogue: swizzled LDS writes (2-way banks), coalesced 16B stores ----
    __syncthreads();
#pragma unroll
    for (int mt = 0; mt < 4; mt++)
#pragma unroll
      for (int r = 0; r < 4; r++) {
        int row = msub + mt * 16 + quad * 4 + r;
#pragma unroll
        for (int nt = 0; nt < 4; nt++) {
          int c = nsub + nt * 16 + col;
          float v = acc[mt][nt][r] + (BIAS ? bias[n0 + c] : 0.f);
          smem[row * 128 + (((c >> 3) ^ (quad << 1)) * 8) + (c & 7)] = f2bf(v);
        }
      }
    __syncthreads();
#pragma unroll
    for (int pass = 0; pass < 8; pass++) {
      int row = pass * 16 + (tid >> 4);
      int sw  = ((row >> 2) & 3) << 1;
      int ch  = tid & 15;
      u16x8 vv = *(const u16x8*)&smem[row * 128 + ((ch ^ sw) * 8)];
      int drow = REMAP ? remap[m0 + row] : (m0 + row);
      *(u16x8*)(Cbf + (size_t)drow * NCOLS + n0 + ch * 8) = vv;
    }
  } else {
    // ---- fp32 epilogue: two 64-row half-tiles via LDS, 128B-coalesced f32x4 stores ----
    float* smemf = (float*)smem;   // 64 x 128 f32 = 32 KB per half
    float bv[4];
#pragma unroll
    for (int nt = 0; nt < 4; nt++) bv[nt] = BIAS ? bias[n0 + nsub + nt * 16 + col] : 0.f;
#pragma unroll
    for (int hh = 0; hh < 2; hh++) {
      __syncthreads();
      if ((wv & 1) == hh) {
#pragma unroll
        for (int mt = 0; mt < 4; mt++)
#pragma unroll
          for (int r = 0; r < 4; r++) {
            int row64 = mt * 16 + quad * 4 + r;     // (row64>>2)&3 == quad
#pragma unroll
            for (int nt = 0; nt < 4; nt++) {
              int c = nsub + nt * 16 + col;
              smemf[row64 * 128 + (c ^ (quad * 16))] = acc[mt][nt][r] + bv[nt];
            }
          }
      }
      __syncthreads();
#pragma unroll
      for (int p = 0; p < 2; p++) {
        int row64 = p * 32 + (tid >> 3);
        int sub = tid & 7;
        int sw = ((row64 >> 2) & 3) * 16;
#pragma unroll
        for (int i = 0; i < 4; i++) {
          int c = sub * 4 + i * 32;
          f32x4 v4 = *(const f32x4*)&smemf[row64 * 128 + (c ^ sw)];
          *(f32x4*)&Cf[(size_t)(m0 + hh * 64 + row64) * NCOLS + n0 + c] = v4;
        }
      }
    }
  }
}

// ---------------- flash attention, no-max softmax, l via ones-MFMA ----------------
// block = 4 waves x 32 queries per (graph, head, 128-query tile); 64-key LDS dbuf tiles.
// K: b128 writes, key-row XOR swizzle. V: transposed in staging, key-PAIR packed b32 writes,
// swizzle kc' = kc ^ (d&7) ^ (d>>3) -> 2-way banks on writes and b128 reads (free).
__global__ __launch_bounds__(256, 3) void fattn_kernel(const unsigned short* __restrict__ qkvp,
                                                       const int* __restrict__ starts,
                                                       unsigned short* __restrict__ obuf) {
  __shared__ unsigned short Kbuf[2][64 * 64];
  __shared__ unsigned short Vbuf[2][64 * 64];   // [dim][key], swizzled
  __shared__ unsigned short Plds[4][32 * 64];
  int g = blockIdx.x, h = blockIdx.y, qt = blockIdx.z;
  int st = starts[g];
  int n  = starts[g + 1] - st;
  int q0b = qt * 128;
  if (q0b >= n) return;  // uniform exit
  int tid = threadIdx.x, lane = tid & 63, wv = tid >> 6;
  int col = lane & 15, quad = lane >> 4;
  int q0 = q0b + wv * 32;
  bool active = q0 < n;
  int ntiles = (n + 63) >> 6;

  // Q fragments (A-layout); pad-row reads are finite poison, results discarded
  bf16x8 qf[2][2];
  if (active) {
#pragma unroll
    for (int a = 0; a < 2; a++) {
      const unsigned short* qp = qkvp + (size_t)(g * NPAD + q0 + a * 16 + col) * 1536 + h * 64 + quad * 8;
      qf[a][0] = *(const bf16x8*)(qp);
      qf[a][1] = *(const bf16x8*)(qp + 32);
    }
  }

  // K staging: thread -> key row srow, chunk pair sc,sc+1
  int srow = tid >> 2;          // 0..63
  int sc   = (tid & 3) * 2;     // 0,2,4,6
  int kwoff0 = srow * 64 + ((sc ^ (srow & 7)) * 8);
  int kwoff1 = srow * 64 + (((sc + 1) ^ (srow & 7)) * 8);
  // V staging: thread -> key pair vkp, dim chunk vdc; packed b32 writes
  int vkp = tid >> 3;           // 0..31
  int vdc = tid & 7;            // 0..7
  int vkc   = vkp >> 2;         // key chunk 0..7
  int vkoff = (vkp & 3) * 2;    // even key offset in chunk
  u16x8 kreg0, kreg1, vreg0, vreg1;
  auto loadregs = [&](int kt) {
    const unsigned short* kp = qkvp + (size_t)(g * NPAD + kt + srow) * 1536 + 512 + h * 64 + sc * 8;
    kreg0 = *(const u16x8*)(kp);
    kreg1 = *(const u16x8*)(kp + 8);
    const unsigned short* vp = qkvp + (size_t)(g * NPAD + kt + 2 * vkp) * 1536 + 1024 + h * 64 + vdc * 8;
    vreg0 = *(const u16x8*)(vp);
    vreg1 = *(const u16x8*)(vp + 1536);
  };
  auto writelds = [&](int bsel) {
    *(u16x8*)&Kbuf[bsel][kwoff0] = kreg0;
    *(u16x8*)&Kbuf[bsel][kwoff1] = kreg1;
#pragma unroll
    for (int i = 0; i < 8; i++) {
      int d = vdc * 8 + i;
      unsigned int pv = (unsigned int)(unsigned short)vreg0[i]
                      | ((unsigned int)(unsigned short)vreg1[i] << 16);
      *(unsigned int*)&Vbuf[bsel][d * 64 + ((vkc ^ (d & 7) ^ (d >> 3)) * 8) + vkoff] = pv;
    }
  };

  // all-ones B-fragment (bf16 1.0): D = P * ones^T gives row-sum l in every column
  bf16x8 onesv;
#pragma unroll
  for (int i = 0; i < 8; i++) onesv[i] = (short)0x3F80;

  f32x4 oa[2][4];
  f32x4 lacc[2];
#pragma unroll
  for (int a = 0; a < 2; a++) {
    lacc[a] = (f32x4){0.f, 0.f, 0.f, 0.f};
#pragma unroll
    for (int i = 0; i < 4; i++) oa[a][i] = (f32x4){0.f, 0.f, 0.f, 0.f};
  }

  loadregs(0);
  writelds(0);
  __syncthreads();

  for (int t = 0; t < ntiles; t++) {
    int cur = t & 1;
    if (t + 1 < ntiles) loadregs((t + 1) * 64);  // prefetch next tile into regs
    if (active) {
      // ---- S = Q K^T over 64 keys ----
      f32x4 s[2][4];
#pragma unroll
      for (int a = 0; a < 2; a++)
#pragma unroll
        for (int j = 0; j < 4; j++) s[a][j] = (f32x4){0.f, 0.f, 0.f, 0.f};
#pragma unroll
      for (int j = 0; j < 4; j++) {
        int R = j * 16 + col;
        bf16x8 kf0 = *(const bf16x8*)&Kbuf[cur][R * 64 + ((quad ^ (R & 7)) * 8)];
        bf16x8 kf1 = *(const bf16x8*)&Kbuf[cur][R * 64 + (((4 + quad) ^ (R & 7)) * 8)];
        s[0][j] = __builtin_amdgcn_mfma_f32_16x16x32_bf16(qf[0][0], kf0, s[0][j], 0, 0, 0);
        s[0][j] = __builtin_amdgcn_mfma_f32_16x16x32_bf16(qf[0][1], kf1, s[0][j], 0, 0, 0);
        s[1][j] = __builtin_amdgcn_mfma_f32_16x16x32_bf16(qf[1][0], kf0, s[1][j], 0, 0, 0);
        s[1][j] = __builtin_amdgcn_mfma_f32_16x16x32_bf16(qf[1][1], kf1, s[1][j], 0, 0, 0);
      }
      // ---- P = exp(S/8), masked; no max subtraction (|S/8| small, fp32 exp safe) ----
      int kt = t * 64;
#pragma unroll
      for (int j = 0; j < 4; j++) {
        bool valid = (kt + j * 16 + col) < n;
#pragma unroll
        for (int a = 0; a < 2; a++)
#pragma unroll
          for (int r = 0; r < 4; r++)
            s[a][j][r] = valid ? __expf(s[a][j][r] * 0.125f) : 0.f;
      }
      // ---- P: C-layout -> A-layout via per-wave LDS (swizzled scalar writes) ----
#pragma unroll
      for (int a = 0; a < 2; a++)
#pragma unroll
        for (int r = 0; r < 4; r++) {
          int R = a * 16 + quad * 4 + r;
#pragma unroll
          for (int j = 0; j < 4; j++) {
            int chunk = j * 2 + (col >> 3);
            Plds[wv][R * 64 + ((chunk ^ (R & 7)) * 8) + (col & 7)] = f2bf(s[a][j][r]);
          }
        }
      __builtin_amdgcn_fence(__ATOMIC_ACQ_REL, "workgroup");
      bf16x8 pf[2][2];
#pragma unroll
      for (int a = 0; a < 2; a++) {
        int R = a * 16 + col;
        pf[a][0] = *(const bf16x8*)&Plds[wv][R * 64 + ((quad ^ (col & 7)) * 8)];
        pf[a][1] = *(const bf16x8*)&Plds[wv][R * 64 + (((4 + quad) ^ (col & 7)) * 8)];
      }
      // ---- O += P V ; l += P * 1 ----
#pragma unroll
      for (int dt = 0; dt < 4; dt++) {
        int R = dt * 16 + col;
        int swz = (R & 7) ^ (R >> 3);
        bf16x8 vf0 = *(const bf16x8*)&Vbuf[cur][R * 64 + ((quad ^ swz) * 8)];
        bf16x8 vf1 = *(const bf16x8*)&Vbuf[cur][R * 64 + (((quad + 4) ^ swz) * 8)];
        oa[0][dt] = __builtin_amdgcn_mfma_f32_16x16x32_bf16(pf[0][0], vf0, oa[0][dt], 0, 0, 0);
        oa[0][dt] = __builtin_amdgcn_mfma_f32_16x16x32_bf16(pf[0][1], vf1, oa[0][dt], 0, 0, 0);
        oa[1][dt] = __builtin_amdgcn_mfma_f32_16x16x32_bf16(pf[1][0], vf0, oa[1][dt], 0, 0, 0);
        oa[1][dt] = __builtin_amdgcn_mfma_f32_16x16x32_bf16(pf[1][1], vf1, oa[1][dt], 0, 0, 0);
      }
      lacc[0] = __builtin_amdgcn_mfma_f32_16x16x32_bf16(pf[0][0], onesv, lacc[0], 0, 0, 0);
      lacc[0] = __builtin_amdgcn_mfma_f32_16x16x32_bf16(pf[0][1], onesv, lacc[0], 0, 0, 0);
      lacc[1] = __builtin_amdgcn_mfma_f32_16x16x32_bf16(pf[1][0], onesv, lacc[1], 0, 0, 0);
      lacc[1] = __builtin_amdgcn_mfma_f32_16x16x32_bf16(pf[1][1], onesv, lacc[1], 0, 0, 0);
    }
    if (t + 1 < ntiles) writelds(1 - cur);
    __syncthreads();
  }

  if (active) {
#pragma unroll
    for (int a = 0; a < 2; a++)
#pragma unroll
      for (int r = 0; r < 4; r++) {
        int q = q0 + a * 16 + quad * 4 + r;
        if (q < n) {
          float inv = 1.0f / lacc[a][r];
          unsigned short* op = obuf + (size_t)(st + q) * DIM + h * 64 + col;
          op[0]  = f2bf(oa[a][0][r] * inv);
          op[16] = f2bf(oa[a][1][r] * inv);
          op[32] = f2bf(oa[a][2][r] * inv);
          op[48] = f2bf(oa[a][3][r] * inv);
        }
      }
  }
}

extern "C" void kernel_launch(void* const* d_in, const int* in_sizes, int n_in,
                              void* d_out, int out_size, void* d_ws, size_t ws_size,
                              hipStream_t stream) {
  const float* z     = (const float*)d_in[0];
  const int*   src   = (const int*)d_in[1];
  const float* gamma = (const float*)d_in[2];
  const float* beta  = (const float*)d_in[3];
  const float* Wq    = (const float*)d_in[4];
  const float* Wk    = (const float*)d_in[5];
  const float* Wv    = (const float*)d_in[6];
  const float* Wo    = (const float*)d_in[7];
  const float* bo    = (const float*)d_in[8];
  int ntot = in_sizes[0] / DIN;
  float* out = (float*)d_out;

  char* ws = (char*)d_ws;
  size_t off = 0;
  unsigned short* zn    = (unsigned short*)(ws + off); off += (size_t)ntot * DIN * 2;
  unsigned short* qkvp  = (unsigned short*)(ws + off); off += (size_t)NPTOT * 1536 * 2;
  unsigned short* obuf  = (unsigned short*)(ws + off); off += (size_t)ntot * DIM * 2;
  unsigned short* WtQKV = (unsigned short*)(ws + off); off += (size_t)1536 * DIN * 2;
  unsigned short* WtO   = (unsigned short*)(ws + off); off += (size_t)DIM * DIN * 2;
  int* starts           = (int*)(ws + off);            off += 64 * 4;
  int* dstrow           = (int*)(ws + off);

  int nln = ntot >> 2;
  int nmap = (ntot + 255) >> 8;
  prep_kernel<<<nln + nmap + 1024, 256, 0, stream>>>(z, gamma, beta, src, Wq, Wk, Wv, Wo,
                                                     zn, starts, dstrow, WtQKV, WtO, ntot);

  // qkvp[g*512+pos][0..1536) = zn @ [Wq|Wk|Wv] (rows scattered to padded slots)
  gemm_staged<1536, false, false, true>
      <<<dim3(ntot / 128, 12), 256, 0, stream>>>(zn, WtQKV, nullptr, dstrow, qkvp, nullptr);

  // flash attention: grid (graphs, heads, 128-query tiles); V transposed in-LDS
  fattn_kernel<<<dim3(NB, NHEADS, 4), 256, 0, stream>>>(qkvp, starts, obuf);

  // out = obuf @ Wo + bo -> fp32
  gemm_staged<512, true, true, false>
      <<<dim3(ntot / 128, 4), 256, 0, stream>>>(obuf, WtO, bo, nullptr, nullptr, out);
}